// Round 1
// baseline (1931.193 us; speedup 1.0000x reference)
//
#include <hip/hip_runtime.h>
#include <cstddef>

// Problem constants
#define BB 64
#define SS 1024
#define DDIM 128
#define NH 4
#define HDIM 32
#define HIDD 512
#define EPSF 1e-5f
#define SCALEF 0.17677669529663687f   // 1/sqrt(32)

// ---------------- K1: LN1 + query/key masks ----------------
__global__ __launch_bounds__(128) void k_ln1(const float* __restrict__ seq,
    const float* __restrict__ g1, const float* __restrict__ be1,
    float* __restrict__ q_in, float* __restrict__ qmask, float* __restrict__ kmask) {
  int row = blockIdx.x, t = threadIdx.x;
  float v = seq[(size_t)row * DDIM + t];
  float s = v, a = fabsf(v);
  #pragma unroll
  for (int o = 32; o; o >>= 1) { s += __shfl_down(s, o); a += __shfl_down(a, o); }
  __shared__ float sm[4], sm2[2], sm3[2];
  if ((t & 63) == 0) { sm[t >> 6] = s; sm[2 + (t >> 6)] = a; }
  __syncthreads();
  float mean = (sm[0] + sm[1]) * (1.f / DDIM);
  float asum = sm[2] + sm[3];
  float d = v - mean;
  float sq = d * d;
  #pragma unroll
  for (int o = 32; o; o >>= 1) sq += __shfl_down(sq, o);
  if ((t & 63) == 0) sm2[t >> 6] = sq;
  __syncthreads();
  float var = (sm2[0] + sm2[1]) * (1.f / DDIM);
  float qv = d * rsqrtf(var + EPSF) * g1[t] + be1[t];
  q_in[(size_t)row * DDIM + t] = qv;
  float aq = fabsf(qv);
  #pragma unroll
  for (int o = 32; o; o >>= 1) aq += __shfl_down(aq, o);
  if ((t & 63) == 0) sm3[t >> 6] = aq;
  __syncthreads();
  if (t == 0) {
    kmask[row] = asum > 0.f ? 1.f : 0.f;
    qmask[row] = (sm3[0] + sm3[1]) > 0.f ? 1.f : 0.f;
  }
}

// ---------------- K2: QKV projections (tiled f32 GEMM) ----------------
// grid (1024, 3), block 256. Tile: 64 rows x 128 cols, K chunked by 32.
__global__ __launch_bounds__(256) void k_qkv(const float* __restrict__ q_in,
    const float* __restrict__ seq,
    const float* __restrict__ Wq, const float* __restrict__ bq,
    const float* __restrict__ Wk, const float* __restrict__ bk,
    const float* __restrict__ Wv, const float* __restrict__ bv,
    float* __restrict__ Qo, float* __restrict__ Ko, float* __restrict__ Vo) {
  __shared__ float As[64 * 33];
  __shared__ float Ws[32 * 128];
  int m = blockIdx.y;
  const float* A = (m == 0) ? q_in : seq;
  const float* W = (m == 0) ? Wq : (m == 1 ? Wk : Wv);
  const float* bias = (m == 0) ? bq : (m == 1 ? bk : bv);
  float* O = (m == 0) ? Qo : (m == 1 ? Ko : Vo);
  int row0 = blockIdx.x * 64;
  int t = threadIdx.x, tx = t & 15, ty = t >> 4;
  float acc[4][8];
  #pragma unroll
  for (int i = 0; i < 4; ++i)
    #pragma unroll
    for (int j = 0; j < 8; ++j) acc[i][j] = 0.f;
  for (int kc = 0; kc < DDIM; kc += 32) {
    __syncthreads();
    {  // A tile 64x32
      int r = t >> 2, cc = (t & 3) * 8;
      const float4* src = (const float4*)(A + (size_t)(row0 + r) * DDIM + kc + cc);
      float4 v0 = src[0], v1 = src[1];
      float* dst = &As[r * 33 + cc];
      dst[0] = v0.x; dst[1] = v0.y; dst[2] = v0.z; dst[3] = v0.w;
      dst[4] = v1.x; dst[5] = v1.y; dst[6] = v1.z; dst[7] = v1.w;
    }
    {  // W tile 32x128
      int wr = t >> 3, wc = (t & 7) * 16;
      const float4* src = (const float4*)(W + (size_t)(kc + wr) * DDIM + wc);
      float4* dst = (float4*)&Ws[wr * 128 + wc];
      #pragma unroll
      for (int i = 0; i < 4; ++i) dst[i] = src[i];
    }
    __syncthreads();
    #pragma unroll 4
    for (int kk = 0; kk < 32; ++kk) {
      float a0 = As[(ty * 4 + 0) * 33 + kk];
      float a1 = As[(ty * 4 + 1) * 33 + kk];
      float a2 = As[(ty * 4 + 2) * 33 + kk];
      float a3 = As[(ty * 4 + 3) * 33 + kk];
      #pragma unroll
      for (int j = 0; j < 8; ++j) {
        float w = Ws[kk * 128 + tx + 16 * j];
        acc[0][j] += a0 * w; acc[1][j] += a1 * w;
        acc[2][j] += a2 * w; acc[3][j] += a3 * w;
      }
    }
  }
  #pragma unroll
  for (int j = 0; j < 8; ++j) {
    int c = tx + 16 * j;
    float bb = bias[c];
    #pragma unroll
    for (int i = 0; i < 4; ++i)
      O[(size_t)(row0 + ty * 4 + i) * DDIM + c] = acc[i][j] + bb;
  }
}

// ---------------- K3: attention ----------------
// grid (64 q-tiles, 4 heads, 64 batch), block 256.
#define SP 1028
__global__ __launch_bounds__(256) void k_attn(const float* __restrict__ Q,
    const float* __restrict__ K, const float* __restrict__ V,
    const float* __restrict__ qmask, const float* __restrict__ kmask,
    float* __restrict__ attn, float* __restrict__ xo) {
  __shared__ float s_lds[16 * SP];   // scores / weights, 64.2 KB
  __shared__ float kv[32 * 36];      // K or V chunk (padded stride 36)
  __shared__ float qt[16 * 36];      // Q tile
  int t = threadIdx.x;
  int q0 = blockIdx.x * 16, h = blockIdx.y, b = blockIdx.z;
  const int kend = q0 + 16;
  const int nch = (kend + 31) >> 5;

  {  // load Q tile 16x32
    int r = t >> 4, d2 = (t & 15) * 2;
    const float* src = Q + (size_t)(b * SS + q0 + r) * DDIM + h * HDIM + d2;
    qt[r * 36 + d2] = src[0];
    qt[r * 36 + d2 + 1] = src[1];
  }
  __syncthreads();
  int pq = t >> 4, pk = t & 15;
  float4 qr[8];
  {
    const float4* q4 = (const float4*)&qt[pq * 36];
    #pragma unroll
    for (int i = 0; i < 8; ++i) qr[i] = q4[i];
  }
  // phase 1: scores
  for (int c = 0; c < nch; ++c) {
    int kc = c * 32;
    __syncthreads();
    {
      int r = t >> 3, cc = (t & 7) * 4;
      *(float4*)&kv[r * 36 + cc] =
          *(const float4*)(K + (size_t)(b * SS + kc + r) * DDIM + h * HDIM + cc);
    }
    __syncthreads();
    float d0 = 0.f, d1 = 0.f;
    const float4* k40 = (const float4*)&kv[pk * 36];
    const float4* k41 = (const float4*)&kv[(pk + 16) * 36];
    #pragma unroll
    for (int i = 0; i < 8; ++i) {
      float4 a = qr[i], x0 = k40[i], x1 = k41[i];
      d0 += a.x * x0.x + a.y * x0.y + a.z * x0.z + a.w * x0.w;
      d1 += a.x * x1.x + a.y * x1.y + a.z * x1.z + a.w * x1.w;
    }
    if (kc + pk < kend) {
      float kmv = kmask[b * SS + kc + pk];
      s_lds[pq * SP + kc + pk] = (kmv != 0.f) ? d0 * SCALEF : -INFINITY;
    }
    if (kc + pk + 16 < kend) {
      float kmv = kmask[b * SS + kc + pk + 16];
      s_lds[pq * SP + kc + pk + 16] = (kmv != 0.f) ? d1 * SCALEF : -INFINITY;
    }
  }
  __syncthreads();
  // phase 2: softmax + write attention weights (one wave per row)
  {
    int w = t >> 6, lane = t & 63;
    for (int rr = 0; rr < 4; ++rr) {
      int r = w + rr * 4;
      int q = q0 + r;
      float qm = qmask[b * SS + q];
      float4 e[4];
      float mx = -INFINITY;
      #pragma unroll
      for (int i = 0; i < 4; ++i) {
        int k4 = (i * 64 + lane) * 4;
        float4 sv = *(const float4*)&s_lds[r * SP + k4];
        float* pv = (float*)&sv;
        float* pe = (float*)&e[i];
        #pragma unroll
        for (int j = 0; j < 4; ++j) {
          int k = k4 + j;
          float vv = (k <= q) ? pv[j] : -INFINITY;
          pe[j] = vv;
          mx = fmaxf(mx, vv);
        }
      }
      #pragma unroll
      for (int o = 32; o; o >>= 1) mx = fmaxf(mx, __shfl_xor(mx, o));
      float sum = 0.f;
      #pragma unroll
      for (int i = 0; i < 4; ++i) {
        float* pe = (float*)&e[i];
        #pragma unroll
        for (int j = 0; j < 4; ++j) {
          float ev = (pe[j] > -INFINITY) ? __expf(pe[j] - mx) : 0.f;
          pe[j] = ev;
          sum += ev;
        }
      }
      #pragma unroll
      for (int o = 32; o; o >>= 1) sum += __shfl_xor(sum, o);
      float inv = (sum > 0.f) ? qm / sum : 0.f;
      size_t base = ((size_t)((b * NH + h) * SS + q)) * SS;
      #pragma unroll
      for (int i = 0; i < 4; ++i) {
        int k4 = (i * 64 + lane) * 4;
        float4 wv = e[i];
        wv.x *= inv; wv.y *= inv; wv.z *= inv; wv.w *= inv;
        *(float4*)&attn[base + k4] = wv;
        *(float4*)&s_lds[r * SP + k4] = wv;
      }
    }
  }
  __syncthreads();
  // phase 3: PV, k-split by 8
  int ksub = t >> 5, qg = (t >> 3) & 3, dg = t & 7;
  float acc[4][4];
  #pragma unroll
  for (int i = 0; i < 4; ++i)
    #pragma unroll
    for (int j = 0; j < 4; ++j) acc[i][j] = 0.f;
  for (int c = 0; c < nch; ++c) {
    int kc = c * 32;
    __syncthreads();
    {
      int r = t >> 3, cc = (t & 7) * 4;
      *(float4*)&kv[r * 36 + cc] =
          *(const float4*)(V + (size_t)(b * SS + kc + r) * DDIM + h * HDIM + cc);
    }
    __syncthreads();
    #pragma unroll
    for (int i = 0; i < 4; ++i) {
      int k = ksub + 8 * i;
      float4 v4 = *(const float4*)&kv[k * 36 + dg * 4];
      float w0 = s_lds[(qg * 4 + 0) * SP + kc + k];
      float w1 = s_lds[(qg * 4 + 1) * SP + kc + k];
      float w2 = s_lds[(qg * 4 + 2) * SP + kc + k];
      float w3 = s_lds[(qg * 4 + 3) * SP + kc + k];
      acc[0][0] += w0 * v4.x; acc[0][1] += w0 * v4.y; acc[0][2] += w0 * v4.z; acc[0][3] += w0 * v4.w;
      acc[1][0] += w1 * v4.x; acc[1][1] += w1 * v4.y; acc[1][2] += w1 * v4.z; acc[1][3] += w1 * v4.w;
      acc[2][0] += w2 * v4.x; acc[2][1] += w2 * v4.y; acc[2][2] += w2 * v4.z; acc[2][3] += w2 * v4.w;
      acc[3][0] += w3 * v4.x; acc[3][1] += w3 * v4.y; acc[3][2] += w3 * v4.z; acc[3][3] += w3 * v4.w;
    }
  }
  __syncthreads();   // done reading s_lds; reuse as reduction scratch
  #pragma unroll
  for (int i = 0; i < 4; ++i)
    #pragma unroll
    for (int j = 0; j < 4; ++j) s_lds[t * 16 + i * 4 + j] = acc[i][j];
  __syncthreads();
  #pragma unroll
  for (int o = 0; o < 2; ++o) {
    int idx = t + o * 256;
    int q = idx >> 5, d = idx & 31;
    int qt_ = q >> 2, jq = q & 3, dt_ = d >> 2, jd = d & 3;
    float sum = 0.f;
    #pragma unroll
    for (int ks = 0; ks < 8; ++ks)
      sum += s_lds[(ks * 32 + qt_ * 8 + dt_) * 16 + jq * 4 + jd];
    xo[(size_t)(b * SS + q0 + q) * DDIM + h * HDIM + d] = sum;
  }
}

// ---------------- K4: residual + LN2 (in place on xo) ----------------
__global__ __launch_bounds__(128) void k_ln2(const float* __restrict__ q_in,
    const float* __restrict__ g2, const float* __restrict__ be2,
    float* __restrict__ x) {
  int row = blockIdx.x, t = threadIdx.x;
  size_t idx = (size_t)row * DDIM + t;
  float v = x[idx] + q_in[idx];
  float s = v;
  #pragma unroll
  for (int o = 32; o; o >>= 1) s += __shfl_down(s, o);
  __shared__ float sm[2], sm2[2];
  if ((t & 63) == 0) sm[t >> 6] = s;
  __syncthreads();
  float mean = (sm[0] + sm[1]) * (1.f / DDIM);
  float d = v - mean;
  float sq = d * d;
  #pragma unroll
  for (int o = 32; o; o >>= 1) sq += __shfl_down(sq, o);
  if ((t & 63) == 0) sm2[t >> 6] = sq;
  __syncthreads();
  float var = (sm2[0] + sm2[1]) * (1.f / DDIM);
  x[idx] = d * rsqrtf(var + EPSF) * g2[t] + be2[t];
}

// ---------------- K5: fused MLP + residual + mask ----------------
// grid 4096, block 256. 16 rows per block; h tile kept in LDS.
__global__ __launch_bounds__(256) void k_mlp(const float* __restrict__ x,
    const float* __restrict__ W1, const float* __restrict__ bm1,
    const float* __restrict__ W2, const float* __restrict__ bm2,
    const float* __restrict__ mask, float* __restrict__ y) {
  __shared__ float xs[16 * 128];
  __shared__ float hs[16 * 516];
  __shared__ float wsm[8192];
  int t = threadIdx.x;
  int row0 = blockIdx.x * 16;
  {
    int r = t >> 4, cc = (t & 15) * 8;
    const float4* src = (const float4*)(x + (size_t)(row0 + r) * DDIM + cc);
    float4* dst = (float4*)&xs[r * 128 + cc];
    dst[0] = src[0]; dst[1] = src[1];
  }
  int c64 = t & 63, rg = t >> 6;
  float acc1[4][8];
  #pragma unroll
  for (int i = 0; i < 4; ++i)
    #pragma unroll
    for (int j = 0; j < 8; ++j) acc1[i][j] = 0.f;
  for (int kc = 0; kc < DDIM; kc += 16) {
    __syncthreads();
    {
      int wr = t >> 4, wc = (t & 15) * 32;
      const float4* src = (const float4*)(W1 + (size_t)(kc + wr) * HIDD + wc);
      float4* dst = (float4*)&wsm[wr * 512 + wc];
      #pragma unroll
      for (int i = 0; i < 8; ++i) dst[i] = src[i];
    }
    __syncthreads();
    #pragma unroll 4
    for (int kk = 0; kk < 16; ++kk) {
      float a0 = xs[(rg * 4 + 0) * 128 + kc + kk];
      float a1 = xs[(rg * 4 + 1) * 128 + kc + kk];
      float a2 = xs[(rg * 4 + 2) * 128 + kc + kk];
      float a3 = xs[(rg * 4 + 3) * 128 + kc + kk];
      #pragma unroll
      for (int j = 0; j < 8; ++j) {
        float w = wsm[kk * 512 + c64 + 64 * j];
        acc1[0][j] += a0 * w; acc1[1][j] += a1 * w;
        acc1[2][j] += a2 * w; acc1[3][j] += a3 * w;
      }
    }
  }
  #pragma unroll
  for (int j = 0; j < 8; ++j) {
    int c = c64 + 64 * j;
    float bb = bm1[c];
    #pragma unroll
    for (int i = 0; i < 4; ++i)
      hs[(rg * 4 + i) * 516 + c] = fmaxf(acc1[i][j] + bb, 0.f);
  }
  int c32 = t & 31, rg2 = t >> 5;
  float acc2[2][4];
  #pragma unroll
  for (int i = 0; i < 2; ++i)
    #pragma unroll
    for (int j = 0; j < 4; ++j) acc2[i][j] = 0.f;
  for (int kc = 0; kc < HIDD; kc += 64) {
    __syncthreads();
    {
      int wr = t >> 2, wc = (t & 3) * 32;
      const float4* src = (const float4*)(W2 + (size_t)(kc + wr) * DDIM + wc);
      float4* dst = (float4*)&wsm[wr * 128 + wc];
      #pragma unroll
      for (int i = 0; i < 8; ++i) dst[i] = src[i];
    }
    __syncthreads();
    #pragma unroll 8
    for (int kk = 0; kk < 64; ++kk) {
      float h0 = hs[rg2 * 516 + kc + kk];
      float h1 = hs[(rg2 + 8) * 516 + kc + kk];
      #pragma unroll
      for (int j = 0; j < 4; ++j) {
        float w = wsm[kk * 128 + c32 + 32 * j];
        acc2[0][j] += h0 * w;
        acc2[1][j] += h1 * w;
      }
    }
  }
  #pragma unroll
  for (int rr = 0; rr < 2; ++rr) {
    int r = rg2 + rr * 8;
    float mk = mask[row0 + r];
    #pragma unroll
    for (int j = 0; j < 4; ++j) {
      int c = c32 + 32 * j;
      y[(size_t)(row0 + r) * DDIM + c] = (acc2[rr][j] + bm2[c] + xs[r * 128 + c]) * mk;
    }
  }
}

// ---------------- launch ----------------
extern "C" void kernel_launch(void* const* d_in, const int* in_sizes, int n_in,
                              void* d_out, int out_size, void* d_ws, size_t ws_size,
                              hipStream_t stream) {
  const float* seq  = (const float*)d_in[0];
  const float* mask = (const float*)d_in[1];
  const float* Wq = (const float*)d_in[2];
  const float* bq = (const float*)d_in[3];
  const float* Wk = (const float*)d_in[4];
  const float* bk = (const float*)d_in[5];
  const float* Wv = (const float*)d_in[6];
  const float* bv = (const float*)d_in[7];
  const float* g1 = (const float*)d_in[8];
  const float* be1 = (const float*)d_in[9];
  const float* g2 = (const float*)d_in[10];
  const float* be2 = (const float*)d_in[11];
  const float* W1 = (const float*)d_in[12];
  const float* bm1 = (const float*)d_in[13];
  const float* W2 = (const float*)d_in[14];
  const float* bm2 = (const float*)d_in[15];

  // workspace layout (floats); total 42,074,112 floats = 168.3 MB
  float* ws   = (float*)d_ws;
  float* q_in = ws;
  float* Qb   = ws + 8388608;
  float* Kb   = ws + 16777216;
  float* Vb   = ws + 25165824;
  float* xb   = ws + 33554432;   // attn_out, then post-LN2 x (in place)
  float* qmk  = ws + 41943040;
  float* kmk  = ws + 42008576;

  float* y    = (float*)d_out;                 // [B*S*D]
  float* attn = y + 8388608;                   // [B*H*S*S]

  hipLaunchKernelGGL(k_ln1, dim3(BB * SS), dim3(128), 0, stream,
                     seq, g1, be1, q_in, qmk, kmk);
  hipLaunchKernelGGL(k_qkv, dim3(1024, 3), dim3(256), 0, stream,
                     q_in, seq, Wq, bq, Wk, bk, Wv, bv, Qb, Kb, Vb);
  hipLaunchKernelGGL(k_attn, dim3(64, NH, BB), dim3(256), 0, stream,
                     Qb, Kb, Vb, qmk, kmk, attn, xb);
  hipLaunchKernelGGL(k_ln2, dim3(BB * SS), dim3(128), 0, stream,
                     q_in, g2, be2, xb);
  hipLaunchKernelGGL(k_mlp, dim3(4096), dim3(256), 0, stream,
                     xb, W1, bm1, W2, bm2, mask, y);
}

// Round 2
// 1208.241 us; speedup vs baseline: 1.5984x; 1.5984x over previous
//
#include <hip/hip_runtime.h>
#include <cstddef>
#include <cstdint>

// Problem constants
#define BB 64
#define SS 1024
#define DDIM 128
#define NH 4
#define HDIM 32
#define HIDD 512
#define EPSF 1e-5f
#define SCALEF 0.17677669529663687f   // 1/sqrt(32)

typedef __attribute__((ext_vector_type(8))) short short8;
typedef __attribute__((ext_vector_type(4))) float f32x4;

__device__ __forceinline__ unsigned short f2bf(float f) {
  unsigned u = __builtin_bit_cast(unsigned, f);
  unsigned r = (u + 0x7FFFu + ((u >> 16) & 1u)) >> 16;
  return (unsigned short)r;
}

// ---------------- K1: LN1 + query/key masks ----------------
__global__ __launch_bounds__(128) void k_ln1(const float* __restrict__ seq,
    const float* __restrict__ g1, const float* __restrict__ be1,
    float* __restrict__ q_in, float* __restrict__ qmask, float* __restrict__ kmask) {
  int row = blockIdx.x, t = threadIdx.x;
  float v = seq[(size_t)row * DDIM + t];
  float s = v, a = fabsf(v);
  #pragma unroll
  for (int o = 32; o; o >>= 1) { s += __shfl_down(s, o); a += __shfl_down(a, o); }
  __shared__ float sm[4], sm2[2], sm3[2];
  if ((t & 63) == 0) { sm[t >> 6] = s; sm[2 + (t >> 6)] = a; }
  __syncthreads();
  float mean = (sm[0] + sm[1]) * (1.f / DDIM);
  float asum = sm[2] + sm[3];
  float d = v - mean;
  float sq = d * d;
  #pragma unroll
  for (int o = 32; o; o >>= 1) sq += __shfl_down(sq, o);
  if ((t & 63) == 0) sm2[t >> 6] = sq;
  __syncthreads();
  float var = (sm2[0] + sm2[1]) * (1.f / DDIM);
  float qv = d * rsqrtf(var + EPSF) * g1[t] + be1[t];
  q_in[(size_t)row * DDIM + t] = qv;
  float aq = fabsf(qv);
  #pragma unroll
  for (int o = 32; o; o >>= 1) aq += __shfl_down(aq, o);
  if ((t & 63) == 0) sm3[t >> 6] = aq;
  __syncthreads();
  if (t == 0) {
    kmask[row] = asum > 0.f ? 1.f : 0.f;
    qmask[row] = (sm3[0] + sm3[1]) > 0.f ? 1.f : 0.f;
  }
}

// ---------------- K2: QKV projections (tiled f32 GEMM, bf16 out) ----------------
__global__ __launch_bounds__(256) void k_qkv(const float* __restrict__ q_in,
    const float* __restrict__ seq,
    const float* __restrict__ Wq, const float* __restrict__ bq,
    const float* __restrict__ Wk, const float* __restrict__ bk,
    const float* __restrict__ Wv, const float* __restrict__ bv,
    unsigned short* __restrict__ Qo, unsigned short* __restrict__ Ko,
    unsigned short* __restrict__ Vo) {
  __shared__ float As[64 * 33];
  __shared__ float Ws[32 * 128];
  int m = blockIdx.y;
  const float* A = (m == 0) ? q_in : seq;
  const float* W = (m == 0) ? Wq : (m == 1 ? Wk : Wv);
  const float* bias = (m == 0) ? bq : (m == 1 ? bk : bv);
  unsigned short* O = (m == 0) ? Qo : (m == 1 ? Ko : Vo);
  int row0 = blockIdx.x * 64;
  int t = threadIdx.x, tx = t & 15, ty = t >> 4;
  float acc[4][8];
  #pragma unroll
  for (int i = 0; i < 4; ++i)
    #pragma unroll
    for (int j = 0; j < 8; ++j) acc[i][j] = 0.f;
  for (int kc = 0; kc < DDIM; kc += 32) {
    __syncthreads();
    {
      int r = t >> 2, cc = (t & 3) * 8;
      const float4* src = (const float4*)(A + (size_t)(row0 + r) * DDIM + kc + cc);
      float4 v0 = src[0], v1 = src[1];
      float* dst = &As[r * 33 + cc];
      dst[0] = v0.x; dst[1] = v0.y; dst[2] = v0.z; dst[3] = v0.w;
      dst[4] = v1.x; dst[5] = v1.y; dst[6] = v1.z; dst[7] = v1.w;
    }
    {
      int wr = t >> 3, wc = (t & 7) * 16;
      const float4* src = (const float4*)(W + (size_t)(kc + wr) * DDIM + wc);
      float4* dst = (float4*)&Ws[wr * 128 + wc];
      #pragma unroll
      for (int i = 0; i < 4; ++i) dst[i] = src[i];
    }
    __syncthreads();
    #pragma unroll 4
    for (int kk = 0; kk < 32; ++kk) {
      float a0 = As[(ty * 4 + 0) * 33 + kk];
      float a1 = As[(ty * 4 + 1) * 33 + kk];
      float a2 = As[(ty * 4 + 2) * 33 + kk];
      float a3 = As[(ty * 4 + 3) * 33 + kk];
      #pragma unroll
      for (int j = 0; j < 8; ++j) {
        float w = Ws[kk * 128 + tx + 16 * j];
        acc[0][j] += a0 * w; acc[1][j] += a1 * w;
        acc[2][j] += a2 * w; acc[3][j] += a3 * w;
      }
    }
  }
  #pragma unroll
  for (int j = 0; j < 8; ++j) {
    int c = tx + 16 * j;
    float bb = bias[c];
    #pragma unroll
    for (int i = 0; i < 4; ++i)
      O[(size_t)(row0 + ty * 4 + i) * DDIM + c] = f2bf(acc[i][j] + bb);
  }
}

// ---------------- K3: attention via MFMA (2-pass flash-style + full weight write) --
// grid (16 q-blocks, 4 heads, 64 batch), block 256 = 4 waves.
// Wave w owns q rows [q0+16w, q0+16w+16). All LDS wave-private: no __syncthreads.
__global__ __launch_bounds__(256) void k_attn_mfma(
    const unsigned short* __restrict__ Q, const unsigned short* __restrict__ K,
    const unsigned short* __restrict__ V,
    const float* __restrict__ qmask, const float* __restrict__ kmask,
    float* __restrict__ attn, float* __restrict__ xo) {
  __shared__ __align__(16) unsigned short Vt[4][32 * 72];  // per wave: V^T [d][k]
  __shared__ __align__(16) unsigned short Wb[4][16 * 88];  // per wave: w [q][k] bf16

  const int t = threadIdx.x;
  const int w = t >> 6, lane = t & 63, lr = lane & 15, lg = lane >> 4;
  const int qi = 15 - (int)blockIdx.x;        // heavy blocks dispatch first
  const int q0 = qi << 6;
  const int h = blockIdx.y, b = blockIdx.z;
  const int kend = q0 + 64;
  const float NEGINF = -__builtin_inff();

  const size_t bS = (size_t)b * SS;
  const unsigned short* Qh = Q + bS * DDIM + h * HDIM;
  const unsigned short* Kh = K + bS * DDIM + h * HDIM;
  const unsigned short* Vh = V + bS * DDIM + h * HDIM;
  float* attn_bh = attn + (size_t)(b * NH + h) * ((size_t)SS * SS);

  // zero-fill attn[q0:q0+64, kend:SS)
  {
    const int cnt4 = (SS - kend) >> 2;
    for (int r = w; r < 64; r += 4) {
      float* rowp = attn_bh + (size_t)(q0 + r) * SS + kend;
      for (int c = lane; c < cnt4; c += 64)
        *(f32x4*)(rowp + (size_t)c * 4) = (f32x4){0.f, 0.f, 0.f, 0.f};
    }
  }

  const int qrowA = q0 + w * 16 + lr;      // A-frag row (Q)
  const int qrow0 = q0 + w * 16 + lg * 4;  // C-layout row base
  const short8 qf = *(const short8*)(Qh + (size_t)qrowA * DDIM + lg * 8);

  // ---- pass 1: online row max + expsum ----
  float m[4], l[4];
  #pragma unroll
  for (int r = 0; r < 4; ++r) { m[r] = NEGINF; l[r] = 0.f; }

  for (int kc = 0; kc < kend; kc += 64) {
    short8 kf[4];
    #pragma unroll
    for (int T = 0; T < 4; ++T)
      kf[T] = *(const short8*)(Kh + (size_t)(kc + T * 16 + lr) * DDIM + lg * 8);
    f32x4 acc[4];
    #pragma unroll
    for (int T = 0; T < 4; ++T)
      acc[T] = __builtin_amdgcn_mfma_f32_16x16x32_bf16(qf, kf[T],
                                                       (f32x4){0.f, 0.f, 0.f, 0.f}, 0, 0, 0);
    float km[4];
    #pragma unroll
    for (int T = 0; T < 4; ++T) km[T] = kmask[bS + kc + T * 16 + lr];
    float sv[4][4];
    #pragma unroll
    for (int T = 0; T < 4; ++T) {
      const int kcol = kc + T * 16 + lr;
      const bool kz = (km[T] == 0.f);
      #pragma unroll
      for (int r = 0; r < 4; ++r) {
        float s = acc[T][r] * SCALEF;
        sv[T][r] = (kz || kcol > qrow0 + r) ? NEGINF : s;
      }
    }
    #pragma unroll
    for (int r = 0; r < 4; ++r) {
      float pm = fmaxf(fmaxf(sv[0][r], sv[1][r]), fmaxf(sv[2][r], sv[3][r]));
      #pragma unroll
      for (int o = 1; o < 16; o <<= 1) pm = fmaxf(pm, __shfl_xor(pm, o));
      const float mn = fmaxf(m[r], pm);
      float pe = 0.f;
      #pragma unroll
      for (int T = 0; T < 4; ++T)
        pe += (sv[T][r] == NEGINF) ? 0.f : __expf(sv[T][r] - mn);
      #pragma unroll
      for (int o = 1; o < 16; o <<= 1) pe += __shfl_xor(pe, o);
      const float so = (m[r] == NEGINF) ? 0.f : __expf(m[r] - mn);
      l[r] = l[r] * so + pe;
      m[r] = mn;
    }
  }

  float inv[4];
  #pragma unroll
  for (int r = 0; r < 4; ++r) {
    const float qm = qmask[bS + qrow0 + r];
    inv[r] = (l[r] > 0.f) ? qm / l[r] : 0.f;
  }

  // ---- pass 2: recompute scores, write weights, PV via MFMA ----
  unsigned short* myVt = &Vt[w][0];
  unsigned short* myW = &Wb[w][0];
  f32x4 o0 = {0.f, 0.f, 0.f, 0.f}, o1 = {0.f, 0.f, 0.f, 0.f};

  for (int kc = 0; kc < kend; kc += 64) {
    // stage V transposed: Vt[d][k] (row stride 72), lane owns k-row kc+lane
    {
      const unsigned short* vr = Vh + (size_t)(kc + lane) * DDIM;
      short8 a0 = *(const short8*)(vr);
      short8 a1 = *(const short8*)(vr + 8);
      short8 a2 = *(const short8*)(vr + 16);
      short8 a3 = *(const short8*)(vr + 24);
      #pragma unroll
      for (int j = 0; j < 8; ++j) myVt[(j)      * 72 + lane] = (unsigned short)a0[j];
      #pragma unroll
      for (int j = 0; j < 8; ++j) myVt[(8 + j)  * 72 + lane] = (unsigned short)a1[j];
      #pragma unroll
      for (int j = 0; j < 8; ++j) myVt[(16 + j) * 72 + lane] = (unsigned short)a2[j];
      #pragma unroll
      for (int j = 0; j < 8; ++j) myVt[(24 + j) * 72 + lane] = (unsigned short)a3[j];
    }
    short8 kf[4];
    #pragma unroll
    for (int T = 0; T < 4; ++T)
      kf[T] = *(const short8*)(Kh + (size_t)(kc + T * 16 + lr) * DDIM + lg * 8);
    f32x4 acc[4];
    #pragma unroll
    for (int T = 0; T < 4; ++T)
      acc[T] = __builtin_amdgcn_mfma_f32_16x16x32_bf16(qf, kf[T],
                                                       (f32x4){0.f, 0.f, 0.f, 0.f}, 0, 0, 0);
    float km[4];
    #pragma unroll
    for (int T = 0; T < 4; ++T) km[T] = kmask[bS + kc + T * 16 + lr];
    float wv[4][4];
    #pragma unroll
    for (int T = 0; T < 4; ++T) {
      const int kcol = kc + T * 16 + lr;
      const bool kz = (km[T] == 0.f);
      #pragma unroll
      for (int r = 0; r < 4; ++r) {
        float s = acc[T][r] * SCALEF;
        s = (kz || kcol > qrow0 + r) ? NEGINF : s;
        wv[T][r] = (s == NEGINF) ? 0.f : __expf(s - m[r]) * inv[r];
      }
    }
    // write f32 weights to global
    #pragma unroll
    for (int T = 0; T < 4; ++T)
      #pragma unroll
      for (int r = 0; r < 4; ++r)
        attn_bh[(size_t)(qrow0 + r) * SS + (kc + T * 16 + lr)] = wv[T][r];
    // write bf16 weights to LDS for the PV A-fragment transpose
    #pragma unroll
    for (int T = 0; T < 4; ++T)
      #pragma unroll
      for (int r = 0; r < 4; ++r)
        myW[(lg * 4 + r) * 88 + T * 16 + lr] = f2bf(wv[T][r]);
    // PV fragments + MFMA
    const short8 af0 = *(const short8*)(myW + lr * 88 + lg * 8);
    const short8 af1 = *(const short8*)(myW + lr * 88 + 32 + lg * 8);
    const short8 vb00 = *(const short8*)(myVt + (size_t)(lr) * 72 + lg * 8);
    const short8 vb10 = *(const short8*)(myVt + (size_t)(lr) * 72 + 32 + lg * 8);
    const short8 vb01 = *(const short8*)(myVt + (size_t)(16 + lr) * 72 + lg * 8);
    const short8 vb11 = *(const short8*)(myVt + (size_t)(16 + lr) * 72 + 32 + lg * 8);
    o0 = __builtin_amdgcn_mfma_f32_16x16x32_bf16(af0, vb00, o0, 0, 0, 0);
    o0 = __builtin_amdgcn_mfma_f32_16x16x32_bf16(af1, vb10, o0, 0, 0, 0);
    o1 = __builtin_amdgcn_mfma_f32_16x16x32_bf16(af0, vb01, o1, 0, 0, 0);
    o1 = __builtin_amdgcn_mfma_f32_16x16x32_bf16(af1, vb11, o1, 0, 0, 0);
  }

  #pragma unroll
  for (int r = 0; r < 4; ++r) {
    float* op = xo + (bS + qrow0 + r) * DDIM + h * HDIM;
    op[lr] = o0[r];
    op[16 + lr] = o1[r];
  }
}

// ---------------- K4: residual + LN2 (in place on xo) ----------------
__global__ __launch_bounds__(128) void k_ln2(const float* __restrict__ q_in,
    const float* __restrict__ g2, const float* __restrict__ be2,
    float* __restrict__ x) {
  int row = blockIdx.x, t = threadIdx.x;
  size_t idx = (size_t)row * DDIM + t;
  float v = x[idx] + q_in[idx];
  float s = v;
  #pragma unroll
  for (int o = 32; o; o >>= 1) s += __shfl_down(s, o);
  __shared__ float sm[2], sm2[2];
  if ((t & 63) == 0) sm[t >> 6] = s;
  __syncthreads();
  float mean = (sm[0] + sm[1]) * (1.f / DDIM);
  float d = v - mean;
  float sq = d * d;
  #pragma unroll
  for (int o = 32; o; o >>= 1) sq += __shfl_down(sq, o);
  if ((t & 63) == 0) sm2[t >> 6] = sq;
  __syncthreads();
  float var = (sm2[0] + sm2[1]) * (1.f / DDIM);
  x[idx] = d * rsqrtf(var + EPSF) * g2[t] + be2[t];
}

// ---------------- K5: fused MLP + residual + mask ----------------
__global__ __launch_bounds__(256) void k_mlp(const float* __restrict__ x,
    const float* __restrict__ W1, const float* __restrict__ bm1,
    const float* __restrict__ W2, const float* __restrict__ bm2,
    const float* __restrict__ mask, float* __restrict__ y) {
  __shared__ float xs[16 * 128];
  __shared__ float hs[16 * 516];
  __shared__ float wsm[8192];
  int t = threadIdx.x;
  int row0 = blockIdx.x * 16;
  {
    int r = t >> 4, cc = (t & 15) * 8;
    const float4* src = (const float4*)(x + (size_t)(row0 + r) * DDIM + cc);
    float4* dst = (float4*)&xs[r * 128 + cc];
    dst[0] = src[0]; dst[1] = src[1];
  }
  int c64 = t & 63, rg = t >> 6;
  float acc1[4][8];
  #pragma unroll
  for (int i = 0; i < 4; ++i)
    #pragma unroll
    for (int j = 0; j < 8; ++j) acc1[i][j] = 0.f;
  for (int kc = 0; kc < DDIM; kc += 16) {
    __syncthreads();
    {
      int wr = t >> 4, wc = (t & 15) * 32;
      const float4* src = (const float4*)(W1 + (size_t)(kc + wr) * HIDD + wc);
      float4* dst = (float4*)&wsm[wr * 512 + wc];
      #pragma unroll
      for (int i = 0; i < 8; ++i) dst[i] = src[i];
    }
    __syncthreads();
    #pragma unroll 4
    for (int kk = 0; kk < 16; ++kk) {
      float a0 = xs[(rg * 4 + 0) * 128 + kc + kk];
      float a1 = xs[(rg * 4 + 1) * 128 + kc + kk];
      float a2 = xs[(rg * 4 + 2) * 128 + kc + kk];
      float a3 = xs[(rg * 4 + 3) * 128 + kc + kk];
      #pragma unroll
      for (int j = 0; j < 8; ++j) {
        float w = wsm[kk * 512 + c64 + 64 * j];
        acc1[0][j] += a0 * w; acc1[1][j] += a1 * w;
        acc1[2][j] += a2 * w; acc1[3][j] += a3 * w;
      }
    }
  }
  #pragma unroll
  for (int j = 0; j < 8; ++j) {
    int c = c64 + 64 * j;
    float bb = bm1[c];
    #pragma unroll
    for (int i = 0; i < 4; ++i)
      hs[(rg * 4 + i) * 516 + c] = fmaxf(acc1[i][j] + bb, 0.f);
  }
  int c32 = t & 31, rg2 = t >> 5;
  float acc2[2][4];
  #pragma unroll
  for (int i = 0; i < 2; ++i)
    #pragma unroll
    for (int j = 0; j < 4; ++j) acc2[i][j] = 0.f;
  for (int kc = 0; kc < HIDD; kc += 64) {
    __syncthreads();
    {
      int wr = t >> 2, wc = (t & 3) * 32;
      const float4* src = (const float4*)(W2 + (size_t)(kc + wr) * DDIM + wc);
      float4* dst = (float4*)&wsm[wr * 128 + wc];
      #pragma unroll
      for (int i = 0; i < 8; ++i) dst[i] = src[i];
    }
    __syncthreads();
    #pragma unroll 8
    for (int kk = 0; kk < 64; ++kk) {
      float h0 = hs[rg2 * 516 + kc + kk];
      float h1 = hs[(rg2 + 8) * 516 + kc + kk];
      #pragma unroll
      for (int j = 0; j < 4; ++j) {
        float w = wsm[kk * 128 + c32 + 32 * j];
        acc2[0][j] += h0 * w;
        acc2[1][j] += h1 * w;
      }
    }
  }
  #pragma unroll
  for (int rr = 0; rr < 2; ++rr) {
    int r = rg2 + rr * 8;
    float mk = mask[row0 + r];
    #pragma unroll
    for (int j = 0; j < 4; ++j) {
      int c = c32 + 32 * j;
      y[(size_t)(row0 + r) * DDIM + c] = (acc2[rr][j] + bm2[c] + xs[r * 128 + c]) * mk;
    }
  }
}

// ---------------- launch ----------------
extern "C" void kernel_launch(void* const* d_in, const int* in_sizes, int n_in,
                              void* d_out, int out_size, void* d_ws, size_t ws_size,
                              hipStream_t stream) {
  const float* seq  = (const float*)d_in[0];
  const float* mask = (const float*)d_in[1];
  const float* Wq = (const float*)d_in[2];
  const float* bq = (const float*)d_in[3];
  const float* Wk = (const float*)d_in[4];
  const float* bk = (const float*)d_in[5];
  const float* Wv = (const float*)d_in[6];
  const float* bv = (const float*)d_in[7];
  const float* g1 = (const float*)d_in[8];
  const float* be1 = (const float*)d_in[9];
  const float* g2 = (const float*)d_in[10];
  const float* be2 = (const float*)d_in[11];
  const float* W1 = (const float*)d_in[12];
  const float* bm1 = (const float*)d_in[13];
  const float* W2 = (const float*)d_in[14];
  const float* bm2 = (const float*)d_in[15];

  // workspace layout
  float* ws   = (float*)d_ws;
  float* q_in = ws;                                   // 8,388,608 f32
  float* xb   = ws + 8388608;                         // 8,388,608 f32
  float* qmk  = ws + 16777216;                        // 65,536 f32
  float* kmk  = ws + 16842752;                        // 65,536 f32
  unsigned short* Qb = (unsigned short*)(ws + 16908288);
  unsigned short* Kb = Qb + 8388608;
  unsigned short* Vb = Kb + 8388608;

  float* y    = (float*)d_out;                        // [B*S*D]
  float* attn = y + 8388608;                          // [B*H*S*S]

  hipLaunchKernelGGL(k_ln1, dim3(BB * SS), dim3(128), 0, stream,
                     seq, g1, be1, q_in, qmk, kmk);
  hipLaunchKernelGGL(k_qkv, dim3(1024, 3), dim3(256), 0, stream,
                     q_in, seq, Wq, bq, Wk, bk, Wv, bv, Qb, Kb, Vb);
  hipLaunchKernelGGL(k_attn_mfma, dim3(16, NH, BB), dim3(256), 0, stream,
                     Qb, Kb, Vb, qmk, kmk, attn, xb);
  hipLaunchKernelGGL(k_ln2, dim3(BB * SS), dim3(128), 0, stream,
                     q_in, g2, be2, xb);
  hipLaunchKernelGGL(k_mlp, dim3(4096), dim3(256), 0, stream,
                     xb, W1, bm1, W2, bm2, mask, y);
}

// Round 3
// 833.477 us; speedup vs baseline: 2.3170x; 1.4496x over previous
//
#include <hip/hip_runtime.h>
#include <cstddef>
#include <cstdint>

// Problem constants
#define BB 64
#define SS 1024
#define DDIM 128
#define NH 4
#define HDIM 32
#define HIDD 512
#define EPSF 1e-5f
#define SCALEF 0.17677669529663687f   // 1/sqrt(32)

typedef __attribute__((ext_vector_type(8))) short short8;
typedef __attribute__((ext_vector_type(4))) float f32x4;
typedef unsigned short ushort_t;

__device__ __forceinline__ unsigned short f2bf(float f) {
  unsigned u = __builtin_bit_cast(unsigned, f);
  unsigned r = (u + 0x7FFFu + ((u >> 16) & 1u)) >> 16;
  return (unsigned short)r;
}

// ---------------- K0: convert + transpose weights to bf16 ----------------
// WT[n][k] = W[k][n].  grid 256 x 256 threads covers 65536 ids.
__global__ __launch_bounds__(256) void k_cvtw(
    const float* __restrict__ Wq, const float* __restrict__ Wk,
    const float* __restrict__ Wv, const float* __restrict__ W1,
    const float* __restrict__ W2,
    ushort_t* __restrict__ WqT, ushort_t* __restrict__ WkT,
    ushort_t* __restrict__ WvT, ushort_t* __restrict__ W1T,
    ushort_t* __restrict__ W2T) {
  int t = blockIdx.x * 256 + threadIdx.x;
  if (t < 16384) {
    int n = t >> 7, k = t & 127;
    WqT[t] = f2bf(Wq[k * DDIM + n]);
    WkT[t] = f2bf(Wk[k * DDIM + n]);
    WvT[t] = f2bf(Wv[k * DDIM + n]);
  }
  {
    int n = t >> 7, k = t & 127;           // W1T [512][128]
    W1T[t] = f2bf(W1[k * HIDD + n]);
  }
  {
    int n = t >> 9, k = t & 511;           // W2T [128][512]
    W2T[t] = f2bf(W2[k * DDIM + n]);
  }
}

// ---------------- K1: LN1 + query/key masks + bf16 copies ----------------
__global__ __launch_bounds__(128) void k_ln1(const float* __restrict__ seq,
    const float* __restrict__ g1, const float* __restrict__ be1,
    float* __restrict__ q_in, ushort_t* __restrict__ q_in16,
    ushort_t* __restrict__ seq16,
    float* __restrict__ qmask, float* __restrict__ kmask) {
  int row = blockIdx.x, t = threadIdx.x;
  float v = seq[(size_t)row * DDIM + t];
  float s = v, a = fabsf(v);
  #pragma unroll
  for (int o = 32; o; o >>= 1) { s += __shfl_down(s, o); a += __shfl_down(a, o); }
  __shared__ float sm[4], sm2[2], sm3[2];
  if ((t & 63) == 0) { sm[t >> 6] = s; sm[2 + (t >> 6)] = a; }
  __syncthreads();
  float mean = (sm[0] + sm[1]) * (1.f / DDIM);
  float asum = sm[2] + sm[3];
  float d = v - mean;
  float sq = d * d;
  #pragma unroll
  for (int o = 32; o; o >>= 1) sq += __shfl_down(sq, o);
  if ((t & 63) == 0) sm2[t >> 6] = sq;
  __syncthreads();
  float var = (sm2[0] + sm2[1]) * (1.f / DDIM);
  float qv = d * rsqrtf(var + EPSF) * g1[t] + be1[t];
  q_in[(size_t)row * DDIM + t] = qv;
  q_in16[(size_t)row * DDIM + t] = f2bf(qv);
  seq16[(size_t)row * DDIM + t] = f2bf(v);
  float aq = fabsf(qv);
  #pragma unroll
  for (int o = 32; o; o >>= 1) aq += __shfl_down(aq, o);
  if ((t & 63) == 0) sm3[t >> 6] = aq;
  __syncthreads();
  if (t == 0) {
    kmask[row] = asum > 0.f ? 1.f : 0.f;
    qmask[row] = (sm3[0] + sm3[1]) > 0.f ? 1.f : 0.f;
  }
}

// ---------------- K2: QKV projections via MFMA ----------------
// grid (1024, 3), block 256 = 4 waves; wave computes 16 rows x 128 cols.
__global__ __launch_bounds__(256) void k_qkv_mfma(
    const ushort_t* __restrict__ q_in16, const ushort_t* __restrict__ seq16,
    const ushort_t* __restrict__ WqT, const ushort_t* __restrict__ WkT,
    const ushort_t* __restrict__ WvT,
    const float* __restrict__ bq, const float* __restrict__ bk,
    const float* __restrict__ bv,
    ushort_t* __restrict__ Qo, ushort_t* __restrict__ Ko,
    ushort_t* __restrict__ Vo) {
  const int m = blockIdx.y;
  const ushort_t* A = (m == 0) ? q_in16 : seq16;
  const ushort_t* WT = (m == 0) ? WqT : (m == 1 ? WkT : WvT);
  const float* bias = (m == 0) ? bq : (m == 1 ? bk : bv);
  ushort_t* O = (m == 0) ? Qo : (m == 1 ? Ko : Vo);
  const int t = threadIdx.x, w = t >> 6, lane = t & 63;
  const int lr = lane & 15, lg = lane >> 4;
  const int row = blockIdx.x * 64 + w * 16;

  short8 a[4];
  #pragma unroll
  for (int s = 0; s < 4; ++s)
    a[s] = *(const short8*)(A + (size_t)(row + lr) * DDIM + s * 32 + lg * 8);

  #pragma unroll
  for (int nt = 0; nt < 8; ++nt) {
    f32x4 acc = {0.f, 0.f, 0.f, 0.f};
    #pragma unroll
    for (int s = 0; s < 4; ++s) {
      short8 b = *(const short8*)(WT + (size_t)(nt * 16 + lr) * DDIM + s * 32 + lg * 8);
      acc = __builtin_amdgcn_mfma_f32_16x16x32_bf16(a[s], b, acc, 0, 0, 0);
    }
    const int col = nt * 16 + lr;
    const float bb = bias[col];
    #pragma unroll
    for (int r = 0; r < 4; ++r)
      O[(size_t)(row + lg * 4 + r) * DDIM + col] = f2bf(acc[r] + bb);
  }
}

// ---------------- K3: attention via MFMA (2-pass flash-style + full weight write) --
__global__ __launch_bounds__(256) void k_attn_mfma(
    const ushort_t* __restrict__ Q, const ushort_t* __restrict__ K,
    const ushort_t* __restrict__ V,
    const float* __restrict__ qmask, const float* __restrict__ kmask,
    float* __restrict__ attn, float* __restrict__ xo) {
  __shared__ __align__(16) ushort_t Vt[4][32 * 72];  // per wave: V^T [d][k]
  __shared__ __align__(16) ushort_t Wb[4][16 * 88];  // per wave: w [q][k] bf16

  const int t = threadIdx.x;
  const int w = t >> 6, lane = t & 63, lr = lane & 15, lg = lane >> 4;
  const int qi = 15 - (int)blockIdx.x;        // heavy blocks dispatch first
  const int q0 = qi << 6;
  const int h = blockIdx.y, b = blockIdx.z;
  const int kend = q0 + 64;
  const float NEGINF = -__builtin_inff();

  const size_t bS = (size_t)b * SS;
  const ushort_t* Qh = Q + bS * DDIM + h * HDIM;
  const ushort_t* Kh = K + bS * DDIM + h * HDIM;
  const ushort_t* Vh = V + bS * DDIM + h * HDIM;
  float* attn_bh = attn + (size_t)(b * NH + h) * ((size_t)SS * SS);

  // zero-fill attn[q0:q0+64, kend:SS)
  {
    const int cnt4 = (SS - kend) >> 2;
    for (int r = w; r < 64; r += 4) {
      float* rowp = attn_bh + (size_t)(q0 + r) * SS + kend;
      for (int c = lane; c < cnt4; c += 64)
        *(f32x4*)(rowp + (size_t)c * 4) = (f32x4){0.f, 0.f, 0.f, 0.f};
    }
  }

  const int qrowA = q0 + w * 16 + lr;
  const int qrow0 = q0 + w * 16 + lg * 4;
  const short8 qf = *(const short8*)(Qh + (size_t)qrowA * DDIM + lg * 8);

  // ---- pass 1: online row max + expsum ----
  float m[4], l[4];
  #pragma unroll
  for (int r = 0; r < 4; ++r) { m[r] = NEGINF; l[r] = 0.f; }

  for (int kc = 0; kc < kend; kc += 64) {
    short8 kf[4];
    #pragma unroll
    for (int T = 0; T < 4; ++T)
      kf[T] = *(const short8*)(Kh + (size_t)(kc + T * 16 + lr) * DDIM + lg * 8);
    f32x4 acc[4];
    #pragma unroll
    for (int T = 0; T < 4; ++T)
      acc[T] = __builtin_amdgcn_mfma_f32_16x16x32_bf16(qf, kf[T],
                                                       (f32x4){0.f, 0.f, 0.f, 0.f}, 0, 0, 0);
    float km[4];
    #pragma unroll
    for (int T = 0; T < 4; ++T) km[T] = kmask[bS + kc + T * 16 + lr];
    float sv[4][4];
    #pragma unroll
    for (int T = 0; T < 4; ++T) {
      const int kcol = kc + T * 16 + lr;
      const bool kz = (km[T] == 0.f);
      #pragma unroll
      for (int r = 0; r < 4; ++r) {
        float s = acc[T][r] * SCALEF;
        sv[T][r] = (kz || kcol > qrow0 + r) ? NEGINF : s;
      }
    }
    #pragma unroll
    for (int r = 0; r < 4; ++r) {
      float pm = fmaxf(fmaxf(sv[0][r], sv[1][r]), fmaxf(sv[2][r], sv[3][r]));
      #pragma unroll
      for (int o = 1; o < 16; o <<= 1) pm = fmaxf(pm, __shfl_xor(pm, o));
      const float mn = fmaxf(m[r], pm);
      float pe = 0.f;
      #pragma unroll
      for (int T = 0; T < 4; ++T)
        pe += (sv[T][r] == NEGINF) ? 0.f : __expf(sv[T][r] - mn);
      #pragma unroll
      for (int o = 1; o < 16; o <<= 1) pe += __shfl_xor(pe, o);
      const float so = (m[r] == NEGINF) ? 0.f : __expf(m[r] - mn);
      l[r] = l[r] * so + pe;
      m[r] = mn;
    }
  }

  float inv[4];
  #pragma unroll
  for (int r = 0; r < 4; ++r) {
    const float qm = qmask[bS + qrow0 + r];
    inv[r] = (l[r] > 0.f) ? qm / l[r] : 0.f;
  }

  // ---- pass 2: recompute scores, write weights, PV via MFMA ----
  ushort_t* myVt = &Vt[w][0];
  ushort_t* myW = &Wb[w][0];
  f32x4 o0 = {0.f, 0.f, 0.f, 0.f}, o1 = {0.f, 0.f, 0.f, 0.f};

  for (int kc = 0; kc < kend; kc += 64) {
    {
      const ushort_t* vr = Vh + (size_t)(kc + lane) * DDIM;
      short8 a0 = *(const short8*)(vr);
      short8 a1 = *(const short8*)(vr + 8);
      short8 a2 = *(const short8*)(vr + 16);
      short8 a3 = *(const short8*)(vr + 24);
      #pragma unroll
      for (int j = 0; j < 8; ++j) myVt[(j)      * 72 + lane] = (ushort_t)a0[j];
      #pragma unroll
      for (int j = 0; j < 8; ++j) myVt[(8 + j)  * 72 + lane] = (ushort_t)a1[j];
      #pragma unroll
      for (int j = 0; j < 8; ++j) myVt[(16 + j) * 72 + lane] = (ushort_t)a2[j];
      #pragma unroll
      for (int j = 0; j < 8; ++j) myVt[(24 + j) * 72 + lane] = (ushort_t)a3[j];
    }
    short8 kf[4];
    #pragma unroll
    for (int T = 0; T < 4; ++T)
      kf[T] = *(const short8*)(Kh + (size_t)(kc + T * 16 + lr) * DDIM + lg * 8);
    f32x4 acc[4];
    #pragma unroll
    for (int T = 0; T < 4; ++T)
      acc[T] = __builtin_amdgcn_mfma_f32_16x16x32_bf16(qf, kf[T],
                                                       (f32x4){0.f, 0.f, 0.f, 0.f}, 0, 0, 0);
    float km[4];
    #pragma unroll
    for (int T = 0; T < 4; ++T) km[T] = kmask[bS + kc + T * 16 + lr];
    float wv[4][4];
    #pragma unroll
    for (int T = 0; T < 4; ++T) {
      const int kcol = kc + T * 16 + lr;
      const bool kz = (km[T] == 0.f);
      #pragma unroll
      for (int r = 0; r < 4; ++r) {
        float s = acc[T][r] * SCALEF;
        s = (kz || kcol > qrow0 + r) ? NEGINF : s;
        wv[T][r] = (s == NEGINF) ? 0.f : __expf(s - m[r]) * inv[r];
      }
    }
    #pragma unroll
    for (int T = 0; T < 4; ++T)
      #pragma unroll
      for (int r = 0; r < 4; ++r)
        attn_bh[(size_t)(qrow0 + r) * SS + (kc + T * 16 + lr)] = wv[T][r];
    #pragma unroll
    for (int T = 0; T < 4; ++T)
      #pragma unroll
      for (int r = 0; r < 4; ++r)
        myW[(lg * 4 + r) * 88 + T * 16 + lr] = f2bf(wv[T][r]);
    const short8 af0 = *(const short8*)(myW + lr * 88 + lg * 8);
    const short8 af1 = *(const short8*)(myW + lr * 88 + 32 + lg * 8);
    const short8 vb00 = *(const short8*)(myVt + (size_t)(lr) * 72 + lg * 8);
    const short8 vb10 = *(const short8*)(myVt + (size_t)(lr) * 72 + 32 + lg * 8);
    const short8 vb01 = *(const short8*)(myVt + (size_t)(16 + lr) * 72 + lg * 8);
    const short8 vb11 = *(const short8*)(myVt + (size_t)(16 + lr) * 72 + 32 + lg * 8);
    o0 = __builtin_amdgcn_mfma_f32_16x16x32_bf16(af0, vb00, o0, 0, 0, 0);
    o0 = __builtin_amdgcn_mfma_f32_16x16x32_bf16(af1, vb10, o0, 0, 0, 0);
    o1 = __builtin_amdgcn_mfma_f32_16x16x32_bf16(af0, vb01, o1, 0, 0, 0);
    o1 = __builtin_amdgcn_mfma_f32_16x16x32_bf16(af1, vb11, o1, 0, 0, 0);
  }

  #pragma unroll
  for (int r = 0; r < 4; ++r) {
    float* op = xo + (bS + qrow0 + r) * DDIM + h * HDIM;
    op[lr] = o0[r];
    op[16 + lr] = o1[r];
  }
}

// ---------------- K4: residual + LN2 (in place) + bf16 copy ----------------
__global__ __launch_bounds__(128) void k_ln2(const float* __restrict__ q_in,
    const float* __restrict__ g2, const float* __restrict__ be2,
    float* __restrict__ x, ushort_t* __restrict__ x16) {
  int row = blockIdx.x, t = threadIdx.x;
  size_t idx = (size_t)row * DDIM + t;
  float v = x[idx] + q_in[idx];
  float s = v;
  #pragma unroll
  for (int o = 32; o; o >>= 1) s += __shfl_down(s, o);
  __shared__ float sm[2], sm2[2];
  if ((t & 63) == 0) sm[t >> 6] = s;
  __syncthreads();
  float mean = (sm[0] + sm[1]) * (1.f / DDIM);
  float d = v - mean;
  float sq = d * d;
  #pragma unroll
  for (int o = 32; o; o >>= 1) sq += __shfl_down(sq, o);
  if ((t & 63) == 0) sm2[t >> 6] = sq;
  __syncthreads();
  float var = (sm2[0] + sm2[1]) * (1.f / DDIM);
  float out = d * rsqrtf(var + EPSF) * g2[t] + be2[t];
  x[idx] = out;
  x16[idx] = f2bf(out);
}

// ---------------- K5: fused MLP via MFMA + residual + mask ----------------
// grid 1024, block 256 = 4 waves; wave computes 16 rows x 128 cols of y.
__global__ __launch_bounds__(256) void k_mlp_mfma(
    const ushort_t* __restrict__ x16, const float* __restrict__ xf,
    const ushort_t* __restrict__ W1T, const float* __restrict__ bm1,
    const ushort_t* __restrict__ W2T, const float* __restrict__ bm2,
    const float* __restrict__ mask, float* __restrict__ y) {
  __shared__ __align__(16) ushort_t hs[4][16 * 140];
  const int t = threadIdx.x, w = t >> 6, lane = t & 63;
  const int lr = lane & 15, lg = lane >> 4;
  const int row = blockIdx.x * 64 + w * 16;
  ushort_t* myh = &hs[w][0];

  short8 xa[4];
  #pragma unroll
  for (int s = 0; s < 4; ++s)
    xa[s] = *(const short8*)(x16 + (size_t)(row + lr) * DDIM + s * 32 + lg * 8);

  f32x4 yacc[8];
  #pragma unroll
  for (int i = 0; i < 8; ++i) yacc[i] = (f32x4){0.f, 0.f, 0.f, 0.f};

  for (int c = 0; c < 4; ++c) {
    // GEMM1: h = relu(x @ W1[:, c*128 : c*128+128])
    #pragma unroll
    for (int nt = 0; nt < 8; ++nt) {
      f32x4 acc = {0.f, 0.f, 0.f, 0.f};
      #pragma unroll
      for (int s = 0; s < 4; ++s) {
        short8 b = *(const short8*)(W1T + (size_t)(c * 128 + nt * 16 + lr) * DDIM + s * 32 + lg * 8);
        acc = __builtin_amdgcn_mfma_f32_16x16x32_bf16(xa[s], b, acc, 0, 0, 0);
      }
      const int col = c * 128 + nt * 16 + lr;
      const float bb = bm1[col];
      #pragma unroll
      for (int r = 0; r < 4; ++r)
        myh[(lg * 4 + r) * 140 + nt * 16 + lr] = f2bf(fmaxf(acc[r] + bb, 0.f));
    }
    // GEMM2: y += h @ W2[c*128 : c*128+128, :]
    short8 a2[4];
    #pragma unroll
    for (int s = 0; s < 4; ++s)
      a2[s] = *(const short8*)(myh + lr * 140 + s * 32 + lg * 8);
    #pragma unroll
    for (int nt = 0; nt < 8; ++nt) {
      #pragma unroll
      for (int s = 0; s < 4; ++s) {
        short8 b = *(const short8*)(W2T + (size_t)(nt * 16 + lr) * HIDD + c * 128 + s * 32 + lg * 8);
        yacc[nt] = __builtin_amdgcn_mfma_f32_16x16x32_bf16(a2[s], b, yacc[nt], 0, 0, 0);
      }
    }
  }

  #pragma unroll
  for (int nt = 0; nt < 8; ++nt) {
    const int col = nt * 16 + lr;
    const float bb = bm2[col];
    #pragma unroll
    for (int r = 0; r < 4; ++r) {
      const int rr = row + lg * 4 + r;
      y[(size_t)rr * DDIM + col] = (yacc[nt][r] + bb + xf[(size_t)rr * DDIM + col]) * mask[rr];
    }
  }
}

// ---------------- launch ----------------
extern "C" void kernel_launch(void* const* d_in, const int* in_sizes, int n_in,
                              void* d_out, int out_size, void* d_ws, size_t ws_size,
                              hipStream_t stream) {
  const float* seq  = (const float*)d_in[0];
  const float* mask = (const float*)d_in[1];
  const float* Wq = (const float*)d_in[2];
  const float* bq = (const float*)d_in[3];
  const float* Wk = (const float*)d_in[4];
  const float* bk = (const float*)d_in[5];
  const float* Wv = (const float*)d_in[6];
  const float* bv = (const float*)d_in[7];
  const float* g1 = (const float*)d_in[8];
  const float* be1 = (const float*)d_in[9];
  const float* g2 = (const float*)d_in[10];
  const float* be2 = (const float*)d_in[11];
  const float* W1 = (const float*)d_in[12];
  const float* bm1 = (const float*)d_in[13];
  const float* W2 = (const float*)d_in[14];
  const float* bm2 = (const float*)d_in[15];

  // workspace layout (151.9 MB total, < 168 MB known-good)
  float* ws   = (float*)d_ws;
  float* q_in = ws;                                   // 8,388,608 f32
  float* xb   = ws + 8388608;                         // 8,388,608 f32
  float* qmk  = ws + 16777216;                        // 65,536 f32
  float* kmk  = ws + 16842752;                        // 65,536 f32
  ushort_t* sbase  = (ushort_t*)(ws + 16908288);
  ushort_t* Qb     = sbase;                           // 8,388,608 bf16
  ushort_t* Kb     = sbase + 8388608;
  ushort_t* Vb     = sbase + 16777216;
  ushort_t* q_in16 = sbase + 25165824;
  ushort_t* seq16  = sbase + 33554432;
  ushort_t* WqT    = sbase + 41943040;                // 16,384
  ushort_t* WkT    = WqT + 16384;
  ushort_t* WvT    = WkT + 16384;
  ushort_t* W1T    = WvT + 16384;                     // 65,536
  ushort_t* W2T    = W1T + 65536;                     // 65,536
  ushort_t* xb16   = Qb;                              // alias: Qb dead after attn

  float* y    = (float*)d_out;                        // [B*S*D]
  float* attn = y + 8388608;                          // [B*H*S*S]

  hipLaunchKernelGGL(k_cvtw, dim3(256), dim3(256), 0, stream,
                     Wq, Wk, Wv, W1, W2, WqT, WkT, WvT, W1T, W2T);
  hipLaunchKernelGGL(k_ln1, dim3(BB * SS), dim3(128), 0, stream,
                     seq, g1, be1, q_in, q_in16, seq16, qmk, kmk);
  hipLaunchKernelGGL(k_qkv_mfma, dim3(1024, 3), dim3(256), 0, stream,
                     q_in16, seq16, WqT, WkT, WvT, bq, bk, bv, Qb, Kb, Vb);
  hipLaunchKernelGGL(k_attn_mfma, dim3(16, NH, BB), dim3(256), 0, stream,
                     Qb, Kb, Vb, qmk, kmk, attn, xb);
  hipLaunchKernelGGL(k_ln2, dim3(BB * SS), dim3(128), 0, stream,
                     q_in, g2, be2, xb, xb16);
  hipLaunchKernelGGL(k_mlp_mfma, dim3(1024), dim3(256), 0, stream,
                     xb16, xb, W1T, bm1, W2T, bm2, mask, y);
}